// Round 7
// baseline (417.068 us; speedup 1.0000x reference)
//
#include <hip/hip_runtime.h>

// ---------------------------------------------------------------------------
// EncoderDecoderAttentionHead. All GEMMs as A[M,K] @ B[N,K]^T, bf16 MFMA.
// R7: MFR=8 path (kv, e) switched to mfma_f32_32x32x16_bf16 (2382 TF shape
// ceiling vs 2075 for 16x16x32; half the instruction count). Ring-4 LDS,
// 2 phases/K-tile, counted vmcnt, conflict-free granule swizzle, setprio --
// all unchanged from R6. MFR=4 path (q, z) stays on 16x16x32.
// ---------------------------------------------------------------------------

typedef __attribute__((ext_vector_type(8))) __bf16 bf16x8;
typedef __attribute__((ext_vector_type(4))) float f32x4;
typedef __attribute__((ext_vector_type(16))) float f32x16;
typedef __attribute__((ext_vector_type(4))) unsigned short ushort4v;
typedef __attribute__((ext_vector_type(8))) unsigned short ushort8v;

#define S_DIM 4096
#define T_DIM 4096
#define D_DIM 2048

__device__ __forceinline__ unsigned short f2bf(float f) {
    unsigned int u = __float_as_uint(f);
    u += 0x7fffu + ((u >> 16) & 1u);
    return (unsigned short)(u >> 16);
}

__device__ __forceinline__ void block_sync() {
    __builtin_amdgcn_sched_barrier(0);
    __builtin_amdgcn_s_barrier();
    __builtin_amdgcn_sched_barrier(0);
}

#define GL(gptr, sptr)                                                        \
    __builtin_amdgcn_global_load_lds(                                         \
        (__attribute__((address_space(1))) void*)(void*)(gptr),               \
        (__attribute__((address_space(3))) void*)(sptr), 16, 0, 0)

__device__ __forceinline__ f32x4 MFMA16(bf16x8 a, bf16x8 b, f32x4 c) {
    return __builtin_amdgcn_mfma_f32_16x16x32_bf16(a, b, c, 0, 0, 0);
}
__device__ __forceinline__ f32x16 MFMA32(bf16x8 a, bf16x8 b, f32x16 c) {
    return __builtin_amdgcn_mfma_f32_32x32x16_bf16(a, b, c, 0, 0, 0);
}

// ---- f32 -> bf16 convert ---------------------------------------------------
__global__ __launch_bounds__(256)
void k_convert(const float* __restrict__ in, unsigned short* __restrict__ out, long n) {
    long i = ((long)blockIdx.x * blockDim.x + threadIdx.x) * 8;
    const long stride = (long)gridDim.x * blockDim.x * 8;
    for (; i < n; i += stride) {
        float4 a = *(const float4*)(in + i);
        float4 b = *(const float4*)(in + i + 4);
        ushort8v o;
        o[0] = f2bf(a.x); o[1] = f2bf(a.y); o[2] = f2bf(a.z); o[3] = f2bf(a.w);
        o[4] = f2bf(b.x); o[5] = f2bf(b.y); o[6] = f2bf(b.z); o[7] = f2bf(b.w);
        *(ushort8v*)(out + i) = o;
    }
}

// ---- fused: x f32 [R][C] -> bf16 x^T [C][R] AND bf16 x [R][C] ---------------
__global__ __launch_bounds__(256)
void k_transpose_dual(const float* __restrict__ in,
                      unsigned short* __restrict__ outT,
                      unsigned short* __restrict__ outN, int R, int C) {
    __shared__ float tile[32][33];
    const int bx = blockIdx.x * 32;
    const int by = blockIdx.y * 32;
    const int tx = threadIdx.x;
    const int ty = threadIdx.y;
    #pragma unroll
    for (int i = 0; i < 32; i += 8) {
        float v = in[(long)(by + ty + i) * C + bx + tx];
        tile[ty + i][tx] = v;
        outN[(long)(by + ty + i) * C + bx + tx] = f2bf(v);
    }
    __syncthreads();
    #pragma unroll
    for (int i = 0; i < 32; i += 8)
        outT[(long)(bx + ty + i) * R + by + tx] = f2bf(tile[tx][ty + i]);
}

// ---- transpose bf16 [R][C] -> bf16 [C][R] ----------------------------------
__global__ __launch_bounds__(256)
void k_transpose_bf(const unsigned short* __restrict__ in,
                    unsigned short* __restrict__ out, int R, int C) {
    __shared__ unsigned short tile[32][33];
    const int bx = blockIdx.x * 32;
    const int by = blockIdx.y * 32;
    const int tx = threadIdx.x;
    const int ty = threadIdx.y;
    #pragma unroll
    for (int i = 0; i < 32; i += 8)
        tile[ty + i][tx] = in[(long)(by + ty + i) * C + bx + tx];
    __syncthreads();
    #pragma unroll
    for (int i = 0; i < 32; i += 8)
        out[(long)(bx + ty + i) * R + by + tx] = tile[tx][ty + i];
}

// ---- MFR=8 / 32x32x16 segment: one K-tile (BK=32), two 8-MFMA phases --------
// P0: ds B1(cur, nt=1 both kslices); stage A(t+3); BAR; lgkm(2); MFMA nt=0
// P1: ds A(t+1) x8 + B0(t+1) x2 from nxt; stage B(t+3); vm; BAR; lgkm(10);
//     MFMA nt=1
template<bool STG, bool PF, int VMW>
__device__ __forceinline__ void seg32(
    const unsigned short* (&gA)[2], const int (&ldA)[2],
    const unsigned short* (&gB)[2], const int (&ldB)[2],
    const char* cur, const char* nxt, char* stg, int arB, int brB,
    bf16x8 (&Ac)[8], bf16x8 (&B0c)[2], bf16x8 (&B1)[2],
    bf16x8 (&An)[8], bf16x8 (&B0n)[2],
    f32x16 (&acc)[4][2])
{
    // ---------------- phase 0 ----------------
    B1[0] = *(const bf16x8*)(cur + (brB + 2048));
    B1[1] = *(const bf16x8*)(cur + ((brB + 2048) ^ 32));
    if constexpr (STG) {
        GL(gA[0], stg + ldA[0]); gA[0] += 32;
        GL(gA[1], stg + ldA[1]); gA[1] += 32;
    }
    block_sync();
    asm volatile("s_waitcnt lgkmcnt(2)" ::: "memory");
    __builtin_amdgcn_sched_barrier(0);
    __builtin_amdgcn_s_setprio(1);
    #pragma unroll
    for (int mt = 0; mt < 4; ++mt) {
        acc[mt][0] = MFMA32(Ac[mt * 2 + 0], B0c[0], acc[mt][0]);
        acc[mt][0] = MFMA32(Ac[mt * 2 + 1], B0c[1], acc[mt][0]);
    }
    __builtin_amdgcn_s_setprio(0);
    // ---------------- phase 1 ----------------
    if constexpr (PF) {
        #pragma unroll
        for (int mt = 0; mt < 4; ++mt) {
            An[mt * 2 + 0] = *(const bf16x8*)(nxt + (arB + mt * 2048));
            An[mt * 2 + 1] = *(const bf16x8*)(nxt + ((arB + mt * 2048) ^ 32));
        }
        B0n[0] = *(const bf16x8*)(nxt + brB);
        B0n[1] = *(const bf16x8*)(nxt + (brB ^ 32));
    }
    if constexpr (STG) {
        GL(gB[0], stg + ldB[0]); gB[0] += 32;
        GL(gB[1], stg + ldB[1]); gB[1] += 32;
    }
    if constexpr (VMW == 4)      asm volatile("s_waitcnt vmcnt(4)" ::: "memory");
    else if constexpr (VMW == 0) asm volatile("s_waitcnt vmcnt(0)" ::: "memory");
    block_sync();
    if constexpr (PF) asm volatile("s_waitcnt lgkmcnt(10)" ::: "memory");
    else              asm volatile("s_waitcnt lgkmcnt(0)" ::: "memory");
    __builtin_amdgcn_sched_barrier(0);
    __builtin_amdgcn_s_setprio(1);
    #pragma unroll
    for (int mt = 0; mt < 4; ++mt) {
        acc[mt][1] = MFMA32(Ac[mt * 2 + 0], B1[0], acc[mt][1]);
        acc[mt][1] = MFMA32(Ac[mt * 2 + 1], B1[1], acc[mt][1]);
    }
    __builtin_amdgcn_s_setprio(0);
}

// ---- MFR=4 / 16x16x32 segment: one K-tile, one 16-MFMA phase ----------------
template<bool STG, bool PF, int VMW>
__device__ __forceinline__ void seg4(
    const unsigned short* (&gA)[2], const int (&ldA)[2],
    const unsigned short* (&gB)[2], const int (&ldB)[2],
    const char* nxt, char* stg, int arB, int brB,
    bf16x8 (&Ac)[4], bf16x8 (&Bc)[4],
    bf16x8 (&An)[4], bf16x8 (&Bn)[4],
    f32x4 (&acc)[4][4])
{
    if constexpr (PF) {
        #pragma unroll
        for (int m = 0; m < 4; ++m)
            An[m] = *(const bf16x8*)(nxt + arB + m * 1024);
        #pragma unroll
        for (int n = 0; n < 4; ++n)
            Bn[n] = *(const bf16x8*)(nxt + brB + n * 1024);
    }
    if constexpr (STG) {
        GL(gA[0], stg + ldA[0]); gA[0] += 32;
        GL(gB[0], stg + ldB[0]); gB[0] += 32;
        GL(gB[1], stg + ldB[1]); gB[1] += 32;
    }
    if constexpr (VMW == 3)      asm volatile("s_waitcnt vmcnt(3)" ::: "memory");
    else if constexpr (VMW == 0) asm volatile("s_waitcnt vmcnt(0)" ::: "memory");
    block_sync();
    if constexpr (PF) asm volatile("s_waitcnt lgkmcnt(8)" ::: "memory");
    else              asm volatile("s_waitcnt lgkmcnt(0)" ::: "memory");
    __builtin_amdgcn_sched_barrier(0);
    __builtin_amdgcn_s_setprio(1);
    #pragma unroll
    for (int m = 0; m < 4; ++m)
        #pragma unroll
        for (int n = 0; n < 4; ++n)
            acc[m][n] = MFMA16(Ac[m], Bc[n], acc[m][n]);
    __builtin_amdgcn_s_setprio(0);
}

// ---- pipelined bf16 GEMM, C[M,N] = alpha*A[M,K]@B[N,K]^T (+bias[col]) ------
// BM = MFR*32, BN = 256, BK = 32, 8 waves (2Mx4N), wave tile (MFR*16)x64.
// LDS rows are 64B; granule (R,s) holds chunk s^((R>>1)&3) -> conflict-free.
template<int MFR, int OUT_BF16, int HAS_BIAS>
__global__ __launch_bounds__(512, 2)
void k_gemm(const unsigned short* __restrict__ A,
            const unsigned short* __restrict__ B,
            const float* __restrict__ bias,
            void* __restrict__ C,
            int M, int N, int K, float alpha) {
    constexpr int BM   = MFR * 32;
    constexpr int LPTA = (BM * 4) / 512;     // A gloads/thread/tile (2 or 1)
    constexpr int LDSA = BM * 64;            // A region bytes
    constexpr int SLOT = LDSA + 16384;       // + B region (256 rows x 64B)
    extern __shared__ __align__(16) char smem[];

    const int tid = threadIdx.x;
    const int l = tid & 63;
    const int w = tid >> 6;
    const int wr = w >> 2;                   // 0..1
    const int wc = w & 3;                    // 0..3

    // XCD-chunked + 4-col supertile block swizzle (grid always 256, gx%4==0)
    const int gx = gridDim.x, gy = gridDim.y;
    const int flat = blockIdx.y * gx + blockIdx.x;
    const int per = (gx * gy) >> 3;
    const int wid = (flat & 7) * per + (flat >> 3);
    const int sc = wid / (gy * 4);
    const int rm = wid - sc * gy * 4;
    const int by = rm >> 2;
    const int bx = sc * 4 + (rm & 3);

    const long brow = (long)by * BM;
    const long bcol = (long)bx * 256;
    const int NT = K >> 5;

    // staging: granule q -> LDS byte q*16; row R=q>>2, slot s=q&3,
    // source chunk c = s ^ ((R>>1)&3)
    const unsigned short* gA[2];
    int ldA[2];
    #pragma unroll
    for (int j = 0; j < LPTA; ++j) {
        const int q = (w * LPTA + j) * 64 + l;
        const int R = q >> 2;
        const int c = (q & 3) ^ ((R >> 1) & 3);
        gA[j] = A + (brow + R) * (long)K + c * 8;
        ldA[j] = q * 16;
    }
    const unsigned short* gB[2];
    int ldB[2];
    #pragma unroll
    for (int j = 0; j < 2; ++j) {
        const int q = (w * 2 + j) * 64 + l;
        const int R = q >> 2;
        const int c = (q & 3) ^ ((R >> 1) & 3);
        gB[j] = B + (bcol + R) * (long)K + c * 8;
        ldB[j] = LDSA + q * 16;
    }

    char* const b0 = smem;
    char* const b1 = smem + SLOT;
    char* const b2 = smem + 2 * SLOT;
    char* const b3 = smem + 3 * SLOT;

    // prologue: stage tiles 0,1,2 into slots 0,1,2; ensure 0 AND 1 landed
    {
        char* d = smem;
        #pragma unroll
        for (int tt = 0; tt < 3; ++tt) {
            #pragma unroll
            for (int j = 0; j < LPTA; ++j) { GL(gA[j], d + ldA[j]); gA[j] += 32; }
            #pragma unroll
            for (int j = 0; j < 2; ++j)    { GL(gB[j], d + ldB[j]); gB[j] += 32; }
            d += SLOT;
        }
        if constexpr (MFR == 8) asm volatile("s_waitcnt vmcnt(4)" ::: "memory");
        else                    asm volatile("s_waitcnt vmcnt(3)" ::: "memory");
        block_sync();
    }

    if constexpr (MFR == 8) {
        // 32x32x16 path. Frag: row/col = base + (l&31), kchunk c = ks*2+(l>>5),
        // byte = row*64 + ((c ^ ((l>>1)&3))<<4); ks=1 slot = ks=0 slot ^ 32.
        const int hi = l >> 5;
        const int sw = (l >> 1) & 3;
        const int s0 = ((hi ^ sw) << 4);
        const int arB = (wr * 128 + (l & 31)) * 64 + s0;
        const int brB = LDSA + (wc * 64 + (l & 31)) * 64 + s0;

        f32x16 acc[4][2] = {};
        bf16x8 Aa[8], Ab[8], B0a[2], B0b[2], B1[2];
        #pragma unroll
        for (int mt = 0; mt < 4; ++mt) {
            Aa[mt * 2 + 0] = *(const bf16x8*)(b0 + (arB + mt * 2048));
            Aa[mt * 2 + 1] = *(const bf16x8*)(b0 + ((arB + mt * 2048) ^ 32));
        }
        B0a[0] = *(const bf16x8*)(b0 + brB);
        B0a[1] = *(const bf16x8*)(b0 + (brB ^ 32));

        for (int t = 0; t + 8 <= NT; t += 4) {
            seg32<true, true, 4>(gA, ldA, gB, ldB, b0, b1, b3, arB, brB,
                                 Aa, B0a, B1, Ab, B0b, acc);
            seg32<true, true, 4>(gA, ldA, gB, ldB, b1, b2, b0, arB, brB,
                                 Ab, B0b, B1, Aa, B0a, acc);
            seg32<true, true, 4>(gA, ldA, gB, ldB, b2, b3, b1, arB, brB,
                                 Aa, B0a, B1, Ab, B0b, acc);
            seg32<true, true, 4>(gA, ldA, gB, ldB, b3, b0, b2, arB, brB,
                                 Ab, B0b, B1, Aa, B0a, acc);
        }
        // tail: tiles NT-4 .. NT-1
        seg32<true,  true,  4>(gA, ldA, gB, ldB, b0, b1, b3, arB, brB,
                               Aa, B0a, B1, Ab, B0b, acc);
        seg32<false, true,  0>(gA, ldA, gB, ldB, b1, b2, b3, arB, brB,
                               Ab, B0b, B1, Aa, B0a, acc);
        seg32<false, true, -1>(gA, ldA, gB, ldB, b2, b3, b3, arB, brB,
                               Aa, B0a, B1, Ab, B0b, acc);
        seg32<false, false, -1>(gA, ldA, gB, ldB, b3, b0, b3, arB, brB,
                                Ab, B0b, B1, Aa, B0a, acc);

        // epilogue: C/D col = lane&31, row = (reg&3) + 8*(reg>>2) + 4*(l>>5)
        #pragma unroll
        for (int nt = 0; nt < 2; ++nt) {
            const long col = bcol + wc * 64 + nt * 32 + (l & 31);
            const float bb = HAS_BIAS ? bias[col] : 0.0f;
            #pragma unroll
            for (int mt = 0; mt < 4; ++mt) {
                #pragma unroll
                for (int reg = 0; reg < 16; ++reg) {
                    const long row = brow + wr * 128 + mt * 32 +
                                     (reg & 3) + 8 * (reg >> 2) + 4 * hi;
                    const float v = acc[mt][nt][reg] * alpha + bb;
                    if (OUT_BF16)
                        ((unsigned short*)C)[row * N + col] = f2bf(v);
                    else
                        ((float*)C)[row * N + col] = v;
                }
            }
        }
    } else {
        // 16x16x32 path (unchanged from R6)
        const int sAB = (((l >> 4) ^ ((l >> 1) & 3)) << 4);
        const int arB = (wr * (MFR * 16) + (l & 15)) * 64 + sAB;
        const int brB = LDSA + (wc * 64 + (l & 15)) * 64 + sAB;

        f32x4 acc[4][4] = {};
        bf16x8 Aa[4], Ab[4], Ba[4], Bb[4];
        #pragma unroll
        for (int m = 0; m < 4; ++m) Aa[m] = *(const bf16x8*)(b0 + arB + m * 1024);
        #pragma unroll
        for (int n = 0; n < 4; ++n) Ba[n] = *(const bf16x8*)(b0 + brB + n * 1024);

        for (int t = 0; t + 8 <= NT; t += 4) {
            seg4<true, true, 3>(gA, ldA, gB, ldB, b1, b3, arB, brB, Aa, Ba, Ab, Bb, acc);
            seg4<true, true, 3>(gA, ldA, gB, ldB, b2, b0, arB, brB, Ab, Bb, Aa, Ba, acc);
            seg4<true, true, 3>(gA, ldA, gB, ldB, b3, b1, arB, brB, Aa, Ba, Ab, Bb, acc);
            seg4<true, true, 3>(gA, ldA, gB, ldB, b0, b2, arB, brB, Ab, Bb, Aa, Ba, acc);
        }
        seg4<true,  true,  3>(gA, ldA, gB, ldB, b1, b3, arB, brB, Aa, Ba, Ab, Bb, acc);
        seg4<false, true,  0>(gA, ldA, gB, ldB, b2, b3, arB, brB, Ab, Bb, Aa, Ba, acc);
        seg4<false, true, -1>(gA, ldA, gB, ldB, b3, b3, arB, brB, Aa, Ba, Ab, Bb, acc);
        seg4<false, false, -1>(gA, ldA, gB, ldB, b3, b3, arB, brB, Ab, Bb, Aa, Ba, acc);

        const long crow0 = brow + wr * (MFR * 16) + (l >> 4) * 4;
        const long ccol0 = bcol + wc * 64 + (l & 15);
        #pragma unroll
        for (int n = 0; n < 4; ++n) {
            const long col = ccol0 + n * 16;
            const float bb = HAS_BIAS ? bias[col] : 0.0f;
            #pragma unroll
            for (int m = 0; m < 4; ++m) {
                #pragma unroll
                for (int r = 0; r < 4; ++r) {
                    const long row = crow0 + m * 16 + r;
                    const float v = acc[m][n][r] * alpha + bb;
                    if (OUT_BF16)
                        ((unsigned short*)C)[row * N + col] = f2bf(v);
                    else
                        ((float*)C)[row * N + col] = v;
                }
            }
        }
    }
}

// ---- row softmax: e [S][T] f32 -> a [S][T] bf16 -----------------------------
__global__ __launch_bounds__(256)
void k_softmax(const float* __restrict__ E, unsigned short* __restrict__ A, int T) {
    const long row = blockIdx.x;
    const float* er = E + row * (long)T;
    const int t = threadIdx.x;
    const int l = t & 63;
    const int w = t >> 6;

    float4 v[4];
    float m = -3.4e38f;
    #pragma unroll
    for (int j = 0; j < 4; ++j) {
        v[j] = *(const float4*)(er + j * 1024 + t * 4);
        m = fmaxf(m, fmaxf(fmaxf(v[j].x, v[j].y), fmaxf(v[j].z, v[j].w)));
    }
    #pragma unroll
    for (int o = 32; o > 0; o >>= 1) m = fmaxf(m, __shfl_xor(m, o));

    __shared__ float redm[4];
    __shared__ float reds[4];
    if (l == 0) redm[w] = m;
    __syncthreads();
    m = fmaxf(fmaxf(redm[0], redm[1]), fmaxf(redm[2], redm[3]));

    float s = 0.f;
    #pragma unroll
    for (int j = 0; j < 4; ++j) {
        v[j].x = __expf(v[j].x - m); s += v[j].x;
        v[j].y = __expf(v[j].y - m); s += v[j].y;
        v[j].z = __expf(v[j].z - m); s += v[j].z;
        v[j].w = __expf(v[j].w - m); s += v[j].w;
    }
    #pragma unroll
    for (int o = 32; o > 0; o >>= 1) s += __shfl_xor(s, o);
    if (l == 0) reds[w] = s;
    __syncthreads();
    s = reds[0] + reds[1] + reds[2] + reds[3];
    const float inv = 1.0f / s;

    unsigned short* ar = A + row * (long)T;
    #pragma unroll
    for (int j = 0; j < 4; ++j) {
        ushort4v o4;
        o4[0] = f2bf(v[j].x * inv);
        o4[1] = f2bf(v[j].y * inv);
        o4[2] = f2bf(v[j].z * inv);
        o4[3] = f2bf(v[j].w * inv);
        *(ushort4v*)(ar + j * 1024 + t * 4) = o4;
    }
}

// ---------------------------------------------------------------------------
extern "C" void kernel_launch(void* const* d_in, const int* in_sizes, int n_in,
                              void* d_out, int out_size, void* d_ws, size_t ws_size,
                              hipStream_t stream) {
    const float* x   = (const float*)d_in[0];   // [S][D]
    const float* enc = (const float*)d_in[1];   // [2][T][S]
    const float* Wq  = (const float*)d_in[2];   // [D][D]
    const float* bq  = (const float*)d_in[3];   // [D]
    float* out = (float*)d_out;                 // [S][D]
    char* ws = (char*)d_ws;

    // abf overlaps xT/xbf (dead before softmax). Total footprint 168 MB.
    unsigned short* abf   = (unsigned short*)(ws);                 // [S][T]   32MB (late)
    unsigned short* xT    = (unsigned short*)(ws);                 // [D][S]   16MB (early)
    unsigned short* xbf   = (unsigned short*)(ws + (16L << 20));   // [S][D]   16MB (early)
    unsigned short* wqbf  = (unsigned short*)(ws + (32L << 20));   // [D][D]    8MB
    unsigned short* qbf   = (unsigned short*)(ws + (40L << 20));   // [S][D]   16MB
    unsigned short* kv    = (unsigned short*)(ws + (56L << 20));   // [2T][D]  32MB
    unsigned short* vT    = (unsigned short*)(ws + (88L << 20));   // [D][T]   16MB
    unsigned short* encbf = (unsigned short*)(ws + (104L << 20));  // [2][T][S] 64MB (early)
    float*          e     = (float*)(ws + (104L << 20));           // [S][T]   64MB (reuse)

    k_convert<<<4096, 256, 0, stream>>>(Wq,  wqbf,  (long)D_DIM * D_DIM);
    k_convert<<<4096, 256, 0, stream>>>(enc, encbf, 2L * T_DIM * S_DIM);
    k_transpose_dual<<<dim3(D_DIM / 32, S_DIM / 32), dim3(32, 8), 0, stream>>>(
        x, xT, xbf, S_DIM, D_DIM);

    #define LAUNCH_G(MFRV, OB, HB, Ap, Bp, biasp, Cp, M_, N_, K_, al)                      \
        do {                                                                               \
            constexpr int smemB = (MFRV * 32 * 64 + 16384) * 4;                            \
            hipFuncSetAttribute((const void*)k_gemm<MFRV, OB, HB>,                         \
                                hipFuncAttributeMaxDynamicSharedMemorySize, smemB);        \
            k_gemm<MFRV, OB, HB><<<dim3((N_) / 256, (M_) / (MFRV * 32)), 512, smemB,       \
                                   stream>>>(Ap, Bp, biasp, Cp, M_, N_, K_, al);           \
        } while (0)

    // q = x @ Wq^T + bq            [4096,2048]  grid (8,32)
    LAUNCH_G(4, 1, 1, xbf, wqbf, bq, qbf, S_DIM, D_DIM, D_DIM, 1.0f);
    // kv = enc @ xT^T (k rows 0..T-1, v rows T..2T-1)  [8192,2048]  grid (8,32)
    LAUNCH_G(8, 1, 0, encbf, xT, nullptr, kv, 2 * T_DIM, D_DIM, S_DIM, 1.0f);
    // vT = transpose(v)            [2048,4096]
    k_transpose_bf<<<dim3(D_DIM / 32, T_DIM / 32), dim3(32, 8), 0, stream>>>(
        kv + (long)T_DIM * D_DIM, vT, T_DIM, D_DIM);
    // e = q @ k^T / sqrt(D)        [4096,4096]  grid (16,16), fp32
    LAUNCH_G(8, 0, 0, qbf, kv, nullptr, e, S_DIM, T_DIM, D_DIM, 0.022097086912079608f);
    // a = softmax(e)               [S,T] bf16
    k_softmax<<<S_DIM, 256, 0, stream>>>(e, abf, T_DIM);
    // z = a @ vT^T                 [4096,2048]  grid (8,32), fp32 -> d_out
    LAUNCH_G(4, 0, 0, abf, vT, nullptr, out, S_DIM, D_DIM, T_DIM, 1.0f);
}

// Round 8
// 360.898 us; speedup vs baseline: 1.1556x; 1.1556x over previous
//
#include <hip/hip_runtime.h>

// ---------------------------------------------------------------------------
// EncoderDecoderAttentionHead. All GEMMs as A[M,K] @ B[N,K]^T, bf16 MFMA
// 16x16x32 (R7's 32x32 experiment regressed: dependent MFMA pairs).
// R8 = R6 core + (a) e output bf16 (halves e-write + softmax-read traffic),
// (b) MFR=4 path phase-split like MFR=8, (c) fused x convert+transpose.
// Ring-4 LDS, BK=32, counted vmcnt/lgkmcnt, conflict-free granule swizzle
// (slot = chunk ^ ((row>>1)&3)), setprio, XCD+supertile block swizzle.
// ---------------------------------------------------------------------------

typedef __attribute__((ext_vector_type(8))) __bf16 bf16x8;
typedef __attribute__((ext_vector_type(4))) float f32x4;
typedef __attribute__((ext_vector_type(4))) unsigned short ushort4v;
typedef __attribute__((ext_vector_type(8))) unsigned short ushort8v;

#define S_DIM 4096
#define T_DIM 4096
#define D_DIM 2048

__device__ __forceinline__ unsigned short f2bf(float f) {
    unsigned int u = __float_as_uint(f);
    u += 0x7fffu + ((u >> 16) & 1u);
    return (unsigned short)(u >> 16);
}

__device__ __forceinline__ void block_sync() {
    __builtin_amdgcn_sched_barrier(0);
    __builtin_amdgcn_s_barrier();
    __builtin_amdgcn_sched_barrier(0);
}

#define GL(gptr, sptr)                                                        \
    __builtin_amdgcn_global_load_lds(                                         \
        (__attribute__((address_space(1))) void*)(void*)(gptr),               \
        (__attribute__((address_space(3))) void*)(sptr), 16, 0, 0)

__device__ __forceinline__ f32x4 MFMA16(bf16x8 a, bf16x8 b, f32x4 c) {
    return __builtin_amdgcn_mfma_f32_16x16x32_bf16(a, b, c, 0, 0, 0);
}

// ---- f32 -> bf16 convert ---------------------------------------------------
__global__ __launch_bounds__(256)
void k_convert(const float* __restrict__ in, unsigned short* __restrict__ out, long n) {
    long i = ((long)blockIdx.x * blockDim.x + threadIdx.x) * 8;
    const long stride = (long)gridDim.x * blockDim.x * 8;
    for (; i < n; i += stride) {
        float4 a = *(const float4*)(in + i);
        float4 b = *(const float4*)(in + i + 4);
        ushort8v o;
        o[0] = f2bf(a.x); o[1] = f2bf(a.y); o[2] = f2bf(a.z); o[3] = f2bf(a.w);
        o[4] = f2bf(b.x); o[5] = f2bf(b.y); o[6] = f2bf(b.z); o[7] = f2bf(b.w);
        *(ushort8v*)(out + i) = o;
    }
}

// ---- fused: x f32 [R][C] -> bf16 x^T [C][R] AND bf16 x [R][C] ---------------
__global__ __launch_bounds__(256)
void k_transpose_dual(const float* __restrict__ in,
                      unsigned short* __restrict__ outT,
                      unsigned short* __restrict__ outN, int R, int C) {
    __shared__ float tile[32][33];
    const int bx = blockIdx.x * 32;
    const int by = blockIdx.y * 32;
    const int tx = threadIdx.x;
    const int ty = threadIdx.y;
    #pragma unroll
    for (int i = 0; i < 32; i += 8) {
        float v = in[(long)(by + ty + i) * C + bx + tx];
        tile[ty + i][tx] = v;
        outN[(long)(by + ty + i) * C + bx + tx] = f2bf(v);
    }
    __syncthreads();
    #pragma unroll
    for (int i = 0; i < 32; i += 8)
        outT[(long)(bx + ty + i) * R + by + tx] = f2bf(tile[tx][ty + i]);
}

// ---- transpose bf16 [R][C] -> bf16 [C][R] ----------------------------------
__global__ __launch_bounds__(256)
void k_transpose_bf(const unsigned short* __restrict__ in,
                    unsigned short* __restrict__ out, int R, int C) {
    __shared__ unsigned short tile[32][33];
    const int bx = blockIdx.x * 32;
    const int by = blockIdx.y * 32;
    const int tx = threadIdx.x;
    const int ty = threadIdx.y;
    #pragma unroll
    for (int i = 0; i < 32; i += 8)
        tile[ty + i][tx] = in[(long)(by + ty + i) * C + bx + tx];
    __syncthreads();
    #pragma unroll
    for (int i = 0; i < 32; i += 8)
        out[(long)(bx + ty + i) * R + by + tx] = tile[tx][ty + i];
}

// ---- MFR=8 segment: one K-tile (BK=32), two phases of 16 MFMA ---------------
// P0: ds B23(cur); stage A(t+3); BAR; lgkm(2); MFMA n=0,1 (uses Ac,B01c)
// P1: ds A,B01(t+1 from nxt); stage B(t+3); vm; BAR; lgkm(10); MFMA n=2,3
template<bool STG, bool PF, int VMW>
__device__ __forceinline__ void seg8(
    const unsigned short* (&gA)[2], const int (&ldA)[2],
    const unsigned short* (&gB)[2], const int (&ldB)[2],
    const char* cur, const char* nxt, char* stg, int arB, int brB,
    bf16x8 (&Ac)[8], bf16x8 (&B01c)[2], bf16x8 (&B23)[2],
    bf16x8 (&An)[8], bf16x8 (&B01n)[2],
    f32x4 (&acc)[8][4])
{
    // ---------------- phase 0 ----------------
    B23[0] = *(const bf16x8*)(cur + brB + 2048);
    B23[1] = *(const bf16x8*)(cur + brB + 3072);
    if constexpr (STG) {
        GL(gA[0], stg + ldA[0]); gA[0] += 32;
        GL(gA[1], stg + ldA[1]); gA[1] += 32;
    }
    block_sync();
    asm volatile("s_waitcnt lgkmcnt(2)" ::: "memory");
    __builtin_amdgcn_sched_barrier(0);
    __builtin_amdgcn_s_setprio(1);
    #pragma unroll
    for (int m = 0; m < 8; ++m) {
        acc[m][0] = MFMA16(Ac[m], B01c[0], acc[m][0]);
        acc[m][1] = MFMA16(Ac[m], B01c[1], acc[m][1]);
    }
    __builtin_amdgcn_s_setprio(0);
    // ---------------- phase 1 ----------------
    if constexpr (PF) {
        #pragma unroll
        for (int m = 0; m < 8; ++m)
            An[m] = *(const bf16x8*)(nxt + arB + m * 1024);
        B01n[0] = *(const bf16x8*)(nxt + brB);
        B01n[1] = *(const bf16x8*)(nxt + brB + 1024);
    }
    if constexpr (STG) {
        GL(gB[0], stg + ldB[0]); gB[0] += 32;
        GL(gB[1], stg + ldB[1]); gB[1] += 32;
    }
    if constexpr (VMW == 4)      asm volatile("s_waitcnt vmcnt(4)" ::: "memory");
    else if constexpr (VMW == 0) asm volatile("s_waitcnt vmcnt(0)" ::: "memory");
    block_sync();
    if constexpr (PF) asm volatile("s_waitcnt lgkmcnt(10)" ::: "memory");
    else              asm volatile("s_waitcnt lgkmcnt(0)" ::: "memory");
    __builtin_amdgcn_sched_barrier(0);
    __builtin_amdgcn_s_setprio(1);
    #pragma unroll
    for (int m = 0; m < 8; ++m) {
        acc[m][2] = MFMA16(Ac[m], B23[0], acc[m][2]);
        acc[m][3] = MFMA16(Ac[m], B23[1], acc[m][3]);
    }
    __builtin_amdgcn_s_setprio(0);
}

// ---- MFR=4 segment: one K-tile, two phases of 8 MFMA ------------------------
// P0: ds B23(cur); stage A(t+3); BAR; lgkm(2); MFMA n=0,1
// P1: ds A,B01(t+1 from nxt); stage B(t+3); vm; BAR; lgkm(6); MFMA n=2,3
template<bool STG, bool PF, int VMW>
__device__ __forceinline__ void seg4(
    const unsigned short* (&gA)[2], const int (&ldA)[2],
    const unsigned short* (&gB)[2], const int (&ldB)[2],
    const char* cur, const char* nxt, char* stg, int arB, int brB,
    bf16x8 (&Ac)[4], bf16x8 (&B01c)[2], bf16x8 (&B23)[2],
    bf16x8 (&An)[4], bf16x8 (&B01n)[2],
    f32x4 (&acc)[4][4])
{
    // ---------------- phase 0 ----------------
    B23[0] = *(const bf16x8*)(cur + brB + 2048);
    B23[1] = *(const bf16x8*)(cur + brB + 3072);
    if constexpr (STG) {
        GL(gA[0], stg + ldA[0]); gA[0] += 32;
    }
    block_sync();
    asm volatile("s_waitcnt lgkmcnt(2)" ::: "memory");
    __builtin_amdgcn_sched_barrier(0);
    __builtin_amdgcn_s_setprio(1);
    #pragma unroll
    for (int m = 0; m < 4; ++m) {
        acc[m][0] = MFMA16(Ac[m], B01c[0], acc[m][0]);
        acc[m][1] = MFMA16(Ac[m], B01c[1], acc[m][1]);
    }
    __builtin_amdgcn_s_setprio(0);
    // ---------------- phase 1 ----------------
    if constexpr (PF) {
        #pragma unroll
        for (int m = 0; m < 4; ++m)
            An[m] = *(const bf16x8*)(nxt + arB + m * 1024);
        B01n[0] = *(const bf16x8*)(nxt + brB);
        B01n[1] = *(const bf16x8*)(nxt + brB + 1024);
    }
    if constexpr (STG) {
        GL(gB[0], stg + ldB[0]); gB[0] += 32;
        GL(gB[1], stg + ldB[1]); gB[1] += 32;
    }
    if constexpr (VMW == 3)      asm volatile("s_waitcnt vmcnt(3)" ::: "memory");
    else if constexpr (VMW == 0) asm volatile("s_waitcnt vmcnt(0)" ::: "memory");
    block_sync();
    if constexpr (PF) asm volatile("s_waitcnt lgkmcnt(6)" ::: "memory");
    else              asm volatile("s_waitcnt lgkmcnt(0)" ::: "memory");
    __builtin_amdgcn_sched_barrier(0);
    __builtin_amdgcn_s_setprio(1);
    #pragma unroll
    for (int m = 0; m < 4; ++m) {
        acc[m][2] = MFMA16(Ac[m], B23[0], acc[m][2]);
        acc[m][3] = MFMA16(Ac[m], B23[1], acc[m][3]);
    }
    __builtin_amdgcn_s_setprio(0);
}

// ---- pipelined bf16 GEMM, C[M,N] = alpha*A[M,K]@B[N,K]^T (+bias[col]) ------
// BM = MFR*32, BN = 256, BK = 32, 8 waves (2Mx4N), wave tile (MFR*16)x64.
// LDS rows are 64B; granule (R,s) holds chunk s^((R>>1)&3) -> conflict-free.
template<int MFR, int OUT_BF16, int HAS_BIAS>
__global__ __launch_bounds__(512, 2)
void k_gemm(const unsigned short* __restrict__ A,
            const unsigned short* __restrict__ B,
            const float* __restrict__ bias,
            void* __restrict__ C,
            int M, int N, int K, float alpha) {
    constexpr int BM   = MFR * 32;
    constexpr int LPTA = (BM * 4) / 512;     // A gloads/thread/tile (2 or 1)
    constexpr int LDSA = BM * 64;            // A region bytes
    constexpr int SLOT = LDSA + 16384;       // + B region (256 rows x 64B)
    extern __shared__ __align__(16) char smem[];

    const int tid = threadIdx.x;
    const int l = tid & 63;
    const int w = tid >> 6;
    const int wr = w >> 2;                   // 0..1
    const int wc = w & 3;                    // 0..3

    // XCD-chunked + 4-col supertile block swizzle (grid always 256, gx%4==0)
    const int gx = gridDim.x, gy = gridDim.y;
    const int flat = blockIdx.y * gx + blockIdx.x;
    const int per = (gx * gy) >> 3;
    const int wid = (flat & 7) * per + (flat >> 3);
    const int sc = wid / (gy * 4);
    const int rm = wid - sc * gy * 4;
    const int by = rm >> 2;
    const int bx = sc * 4 + (rm & 3);

    const long brow = (long)by * BM;
    const long bcol = (long)bx * 256;
    const int NT = K >> 5;

    // staging: granule q -> LDS byte q*16; row R=q>>2, slot s=q&3,
    // source chunk c = s ^ ((R>>1)&3)
    const unsigned short* gA[2];
    int ldA[2];
    #pragma unroll
    for (int j = 0; j < LPTA; ++j) {
        const int q = (w * LPTA + j) * 64 + l;
        const int R = q >> 2;
        const int c = (q & 3) ^ ((R >> 1) & 3);
        gA[j] = A + (brow + R) * (long)K + c * 8;
        ldA[j] = q * 16;
    }
    const unsigned short* gB[2];
    int ldB[2];
    #pragma unroll
    for (int j = 0; j < 2; ++j) {
        const int q = (w * 2 + j) * 64 + l;
        const int R = q >> 2;
        const int c = (q & 3) ^ ((R >> 1) & 3);
        gB[j] = B + (bcol + R) * (long)K + c * 8;
        ldB[j] = LDSA + q * 16;
    }

    // ds_read bases: frag row = base + (l&15), chunk = l>>4,
    // byte = row*64 + ((chunk ^ ((row>>1)&3))<<4); frag step = 16 rows = 1024B
    const int sAB = (((l >> 4) ^ ((l >> 1) & 3)) << 4);
    const int arB = (wr * (MFR * 16) + (l & 15)) * 64 + sAB;
    const int brB = LDSA + (wc * 64 + (l & 15)) * 64 + sAB;

    char* const b0 = smem;
    char* const b1 = smem + SLOT;
    char* const b2 = smem + 2 * SLOT;
    char* const b3 = smem + 3 * SLOT;

    // prologue: stage tiles 0,1,2 into slots 0,1,2; ensure 0 AND 1 landed
    {
        char* d = smem;
        #pragma unroll
        for (int tt = 0; tt < 3; ++tt) {
            #pragma unroll
            for (int j = 0; j < LPTA; ++j) { GL(gA[j], d + ldA[j]); gA[j] += 32; }
            #pragma unroll
            for (int j = 0; j < 2; ++j)    { GL(gB[j], d + ldB[j]); gB[j] += 32; }
            d += SLOT;
        }
        if constexpr (MFR == 8) asm volatile("s_waitcnt vmcnt(4)" ::: "memory");
        else                    asm volatile("s_waitcnt vmcnt(3)" ::: "memory");
        block_sync();
    }

    if constexpr (MFR == 8) {
        bf16x8 Aa[8], Ab[8], Ba[2], Bb[2], B23[2];
        #pragma unroll
        for (int m = 0; m < 8; ++m) Aa[m] = *(const bf16x8*)(b0 + arB + m * 1024);
        Ba[0] = *(const bf16x8*)(b0 + brB);
        Ba[1] = *(const bf16x8*)(b0 + brB + 1024);

        f32x4 acc[8][4] = {};
        for (int t = 0; t + 8 <= NT; t += 4) {
            seg8<true, true, 4>(gA, ldA, gB, ldB, b0, b1, b3, arB, brB,
                                Aa, Ba, B23, Ab, Bb, acc);
            seg8<true, true, 4>(gA, ldA, gB, ldB, b1, b2, b0, arB, brB,
                                Ab, Bb, B23, Aa, Ba, acc);
            seg8<true, true, 4>(gA, ldA, gB, ldB, b2, b3, b1, arB, brB,
                                Aa, Ba, B23, Ab, Bb, acc);
            seg8<true, true, 4>(gA, ldA, gB, ldB, b3, b0, b2, arB, brB,
                                Ab, Bb, B23, Aa, Ba, acc);
        }
        // tail: tiles NT-4 .. NT-1
        seg8<true,  true,  4>(gA, ldA, gB, ldB, b0, b1, b3, arB, brB,
                              Aa, Ba, B23, Ab, Bb, acc);
        seg8<false, true,  0>(gA, ldA, gB, ldB, b1, b2, b3, arB, brB,
                              Ab, Bb, B23, Aa, Ba, acc);
        seg8<false, true, -1>(gA, ldA, gB, ldB, b2, b3, b3, arB, brB,
                              Aa, Ba, B23, Ab, Bb, acc);
        seg8<false, false, -1>(gA, ldA, gB, ldB, b3, b0, b3, arB, brB,
                               Ab, Bb, B23, Aa, Ba, acc);

        const long crow0 = brow + wr * 128 + (l >> 4) * 4;
        const long ccol0 = bcol + wc * 64 + (l & 15);
        #pragma unroll
        for (int n = 0; n < 4; ++n) {
            const long col = ccol0 + n * 16;
            const float bb = HAS_BIAS ? bias[col] : 0.0f;
            #pragma unroll
            for (int m = 0; m < 8; ++m) {
                #pragma unroll
                for (int r = 0; r < 4; ++r) {
                    const long row = crow0 + m * 16 + r;
                    const float v = acc[m][n][r] * alpha + bb;
                    if (OUT_BF16)
                        ((unsigned short*)C)[row * N + col] = f2bf(v);
                    else
                        ((float*)C)[row * N + col] = v;
                }
            }
        }
    } else {
        bf16x8 Aa[4], Ab[4], Ba[2], Bb[2], B23[2];
        #pragma unroll
        for (int m = 0; m < 4; ++m) Aa[m] = *(const bf16x8*)(b0 + arB + m * 1024);
        Ba[0] = *(const bf16x8*)(b0 + brB);
        Ba[1] = *(const bf16x8*)(b0 + brB + 1024);

        f32x4 acc[4][4] = {};
        for (int t = 0; t + 8 <= NT; t += 4) {
            seg4<true, true, 3>(gA, ldA, gB, ldB, b0, b1, b3, arB, brB,
                                Aa, Ba, B23, Ab, Bb, acc);
            seg4<true, true, 3>(gA, ldA, gB, ldB, b1, b2, b0, arB, brB,
                                Ab, Bb, B23, Aa, Ba, acc);
            seg4<true, true, 3>(gA, ldA, gB, ldB, b2, b3, b1, arB, brB,
                                Aa, Ba, B23, Ab, Bb, acc);
            seg4<true, true, 3>(gA, ldA, gB, ldB, b3, b0, b2, arB, brB,
                                Ab, Bb, B23, Aa, Ba, acc);
        }
        seg4<true,  true,  3>(gA, ldA, gB, ldB, b0, b1, b3, arB, brB,
                              Aa, Ba, B23, Ab, Bb, acc);
        seg4<false, true,  0>(gA, ldA, gB, ldB, b1, b2, b3, arB, brB,
                              Ab, Bb, B23, Aa, Ba, acc);
        seg4<false, true, -1>(gA, ldA, gB, ldB, b2, b3, b3, arB, brB,
                              Aa, Ba, B23, Ab, Bb, acc);
        seg4<false, false, -1>(gA, ldA, gB, ldB, b3, b0, b3, arB, brB,
                               Ab, Bb, B23, Aa, Ba, acc);

        const long crow0 = brow + wr * 64 + (l >> 4) * 4;
        const long ccol0 = bcol + wc * 64 + (l & 15);
        #pragma unroll
        for (int n = 0; n < 4; ++n) {
            const long col = ccol0 + n * 16;
            const float bb = HAS_BIAS ? bias[col] : 0.0f;
            #pragma unroll
            for (int m = 0; m < 4; ++m) {
                #pragma unroll
                for (int r = 0; r < 4; ++r) {
                    const long row = crow0 + m * 16 + r;
                    const float v = acc[m][n][r] * alpha + bb;
                    if (OUT_BF16)
                        ((unsigned short*)C)[row * N + col] = f2bf(v);
                    else
                        ((float*)C)[row * N + col] = v;
                }
            }
        }
    }
}

// ---- row softmax: e [S][T] bf16 -> a [S][T] bf16 ----------------------------
__global__ __launch_bounds__(256)
void k_softmax_bf(const unsigned short* __restrict__ E,
                  unsigned short* __restrict__ A, int T) {
    const long row = blockIdx.x;
    const unsigned short* er = E + row * (long)T;
    const int t = threadIdx.x;
    const int l = t & 63;
    const int w = t >> 6;

    float v[16];
    float m = -3.4e38f;
    #pragma unroll
    for (int j = 0; j < 2; ++j) {
        ushort8v u = *(const ushort8v*)(er + j * 2048 + t * 8);
        #pragma unroll
        for (int i = 0; i < 8; ++i) {
            v[j * 8 + i] = __uint_as_float((unsigned int)u[i] << 16);
            m = fmaxf(m, v[j * 8 + i]);
        }
    }
    #pragma unroll
    for (int o = 32; o > 0; o >>= 1) m = fmaxf(m, __shfl_xor(m, o));

    __shared__ float redm[4];
    __shared__ float reds[4];
    if (l == 0) redm[w] = m;
    __syncthreads();
    m = fmaxf(fmaxf(redm[0], redm[1]), fmaxf(redm[2], redm[3]));

    float s = 0.f;
    #pragma unroll
    for (int i = 0; i < 16; ++i) {
        v[i] = __expf(v[i] - m);
        s += v[i];
    }
    #pragma unroll
    for (int o = 32; o > 0; o >>= 1) s += __shfl_xor(s, o);
    if (l == 0) reds[w] = s;
    __syncthreads();
    s = reds[0] + reds[1] + reds[2] + reds[3];
    const float inv = 1.0f / s;

    unsigned short* ar = A + row * (long)T;
    #pragma unroll
    for (int j = 0; j < 2; ++j) {
        ushort8v o8;
        #pragma unroll
        for (int i = 0; i < 8; ++i) o8[i] = f2bf(v[j * 8 + i] * inv);
        *(ushort8v*)(ar + j * 2048 + t * 8) = o8;
    }
}

// ---------------------------------------------------------------------------
extern "C" void kernel_launch(void* const* d_in, const int* in_sizes, int n_in,
                              void* d_out, int out_size, void* d_ws, size_t ws_size,
                              hipStream_t stream) {
    const float* x   = (const float*)d_in[0];   // [S][D]
    const float* enc = (const float*)d_in[1];   // [2][T][S]
    const float* Wq  = (const float*)d_in[2];   // [D][D]
    const float* bq  = (const float*)d_in[3];   // [D]
    float* out = (float*)d_out;                 // [S][D]
    char* ws = (char*)d_ws;

    // abf overlaps xT/xbf (dead before softmax). e (bf16) overlaps encbf.
    unsigned short* abf   = (unsigned short*)(ws);                 // [S][T]   32MB (late)
    unsigned short* xT    = (unsigned short*)(ws);                 // [D][S]   16MB (early)
    unsigned short* xbf   = (unsigned short*)(ws + (16L << 20));   // [S][D]   16MB (early)
    unsigned short* wqbf  = (unsigned short*)(ws + (32L << 20));   // [D][D]    8MB
    unsigned short* qbf   = (unsigned short*)(ws + (40L << 20));   // [S][D]   16MB
    unsigned short* kv    = (unsigned short*)(ws + (56L << 20));   // [2T][D]  32MB
    unsigned short* vT    = (unsigned short*)(ws + (88L << 20));   // [D][T]   16MB
    unsigned short* encbf = (unsigned short*)(ws + (104L << 20));  // [2][T][S] 64MB (early)
    unsigned short* ebf   = (unsigned short*)(ws + (104L << 20));  // [S][T]   32MB (reuse)

    k_convert<<<4096, 256, 0, stream>>>(Wq,  wqbf,  (long)D_DIM * D_DIM);
    k_convert<<<4096, 256, 0, stream>>>(enc, encbf, 2L * T_DIM * S_DIM);
    k_transpose_dual<<<dim3(D_DIM / 32, S_DIM / 32), dim3(32, 8), 0, stream>>>(
        x, xT, xbf, S_DIM, D_DIM);

    #define LAUNCH_G(MFRV, OB, HB, Ap, Bp, biasp, Cp, M_, N_, K_, al)                      \
        do {                                                                               \
            constexpr int smemB = (MFRV * 32 * 64 + 16384) * 4;                            \
            hipFuncSetAttribute((const void*)k_gemm<MFRV, OB, HB>,                         \
                                hipFuncAttributeMaxDynamicSharedMemorySize, smemB);        \
            k_gemm<MFRV, OB, HB><<<dim3((N_) / 256, (M_) / (MFRV * 32)), 512, smemB,       \
                                   stream>>>(Ap, Bp, biasp, Cp, M_, N_, K_, al);           \
        } while (0)

    // q = x @ Wq^T + bq            [4096,2048]  grid (8,32)
    LAUNCH_G(4, 1, 1, xbf, wqbf, bq, qbf, S_DIM, D_DIM, D_DIM, 1.0f);
    // kv = enc @ xT^T (k rows 0..T-1, v rows T..2T-1)  [8192,2048]  grid (8,32)
    LAUNCH_G(8, 1, 0, encbf, xT, nullptr, kv, 2 * T_DIM, D_DIM, S_DIM, 1.0f);
    // vT = transpose(v)            [2048,4096]
    k_transpose_bf<<<dim3(D_DIM / 32, T_DIM / 32), dim3(32, 8), 0, stream>>>(
        kv + (long)T_DIM * D_DIM, vT, T_DIM, D_DIM);
    // e = q @ k^T / sqrt(D)        [4096,4096]  grid (16,16), bf16 out
    LAUNCH_G(8, 1, 0, qbf, kv, nullptr, ebf, S_DIM, T_DIM, D_DIM, 0.022097086912079608f);
    // a = softmax(e)               [S,T] bf16
    k_softmax_bf<<<S_DIM, 256, 0, stream>>>(ebf, abf, T_DIM);
    // z = a @ vT^T                 [4096,2048]  grid (8,32), fp32 -> d_out
    LAUNCH_G(4, 0, 0, abf, vT, nullptr, out, S_DIM, D_DIM, T_DIM, 1.0f);
}